// Round 10
// baseline (335.813 us; speedup 1.0000x reference)
//
#include <hip/hip_runtime.h>
#include <hip/hip_bf16.h>

// Gemma attention decode: B=32, L=1, HID=3072, H=16, KV=8, D=256, S=2048
// All fp32. Memory-bound. Measured: attn~185us, fills show 6.8TB/s achievable.
// R10: 4 kernels (rope fused into attn prologue); qkv 512-thr blocks.

#define SCALE_ 0.0625f   // D^-0.5 = 1/16

// workspace layout (float offsets), ~42MB of ~2.1GB ws
// pqkv  : [24][32][8192] split-K partials of qkv gemm (25.2MB)
// po    : [32][32][3072] oproj partials (12.6MB)
// opart : [32][8][8][2][256] attn chunk partials (4MB)  -- NO pqkv alias now
// ml    : [32][8][8][2] float2
#define NKC       24u
#define OFF_PO    (NKC*32u*8192u)            // 6291456
#define OFF_OPART (OFF_PO + 3145728u)        // 9437184
#define OFF_ML    (OFF_OPART + 1048576u)     // 10485760

typedef float f32x4 __attribute__((ext_vector_type(4)));

__device__ inline f32x4 ntl4(const float* p) {
  return __builtin_nontemporal_load((const f32x4*)p);
}
__device__ inline void nts4(float* p, f32x4 v) {
  __builtin_nontemporal_store(v, (f32x4*)p);
}
__device__ inline f32x4 ld4(const float* p) { return *(const f32x4*)p; }

__device__ inline float dot4v(f32x4 a, f32x4 b) {
  return a.x * b.x + a.y * b.y + a.z * b.z + a.w * b.w;
}

// ---------------------------------------------------------------------------
// Kernel A: QKV projection, split-K partials.
// grid = 32 ctiles x 24 K-chunks = 768 blocks; block = 512 thr (8 waves,
// 24 waves/CU). bg(8) -> 4 batches each. Weights NT (single-use).
__global__ __launch_bounds__(512) void qkv_partial_kernel(
    const float* __restrict__ x, const float* __restrict__ wq,
    const float* __restrict__ wk, const float* __restrict__ wv,
    float* __restrict__ pqkv) {
  __shared__ float xls[32][128];            // 16 KB

  const int lane = threadIdx.x & 63;
  const int bg   = threadIdx.x >> 6;        // 0..7 -> batches bg*4..bg*4+3
  const int ctile = blockIdx.x & 31;
  const int kc    = blockIdx.x >> 5;        // 0..23
  const int n = ctile * 256 + lane * 4;

  for (int i = threadIdx.x; i < 1024; i += 512) {
    const int b = i >> 5;
    const int r = i & 31;
    *(f32x4*)(&xls[b][r * 4]) = ld4(x + (size_t)b * 3072 + kc * 128 + r * 4);
  }

  const float* w; int stride, nn;
  if (n < 4096)      { w = wq; stride = 4096; nn = n; }
  else if (n < 6144) { w = wk; stride = 2048; nn = n - 4096; }
  else               { w = wv; stride = 2048; nn = n - 6144; }
  const float* wb = w + (size_t)(kc * 128) * stride + nn;

  f32x4 acc[4];
#pragma unroll
  for (int j = 0; j < 4; ++j) acc[j] = (f32x4){0.f, 0.f, 0.f, 0.f};

  __syncthreads();

  f32x4 wA[4], wB[4];
#define LDW(S, KK)                                                   \
  {                                                                  \
    S[0] = ntl4(wb + (size_t)((KK) + 0) * stride);                   \
    S[1] = ntl4(wb + (size_t)((KK) + 1) * stride);                   \
    S[2] = ntl4(wb + (size_t)((KK) + 2) * stride);                   \
    S[3] = ntl4(wb + (size_t)((KK) + 3) * stride);                   \
  }
#define CMP(S, KK)                                                   \
  {                                                                  \
    _Pragma("unroll")                                                \
    for (int j = 0; j < 4; ++j) {                                    \
      const f32x4 xv = *(const f32x4*)(&xls[bg * 4 + j][(KK)]);      \
      acc[j] += xv.x * S[0];                                         \
      acc[j] += xv.y * S[1];                                         \
      acc[j] += xv.z * S[2];                                         \
      acc[j] += xv.w * S[3];                                         \
    }                                                                \
  }

  LDW(wA, 0);
  for (int k = 0; k < 128; k += 8) {
    LDW(wB, k + 4);
    CMP(wA, k);
    const int kn = (k + 8 < 128) ? (k + 8) : 0;
    LDW(wA, kn);
    CMP(wB, k + 4);
  }
#undef LDW
#undef CMP

#pragma unroll
  for (int j = 0; j < 4; ++j) {
    nts4(pqkv + ((size_t)kc * 32 + bg * 4 + j) * 8192 + n, acc[j]);
  }
}

// ---------------------------------------------------------------------------
// Kernel B (fused): split-K reduce + RoPE prologue, then flash-decode chunk.
// grid = 2048: bkv = blockIdx&255 (b*8+kv), c = blockIdx>>8 (chunk 0..7)
// -> the 8 chunk-blocks of one (b,kv) share blockIdx%8 -> same XCD L2.
__global__ __launch_bounds__(256) void attn_fused_kernel(
    const float* __restrict__ pqkv, const float* __restrict__ fcos,
    const float* __restrict__ fsin, const float* __restrict__ cache_k,
    const float* __restrict__ cache_v, const float* __restrict__ mask,
    const int* __restrict__ posp, float* __restrict__ opart,
    float* __restrict__ ml) {
  __shared__ float accraw[8][512];   // 16 KB: prologue raw[4][256] / epi accbuf
  __shared__ float xv[4][256];       // 4 KB: roped q0,q1,k,v
  __shared__ float mred[8][4];

  const int tid = threadIdx.x, lane = tid & 63, wv = tid >> 6;
  const int sub = lane & 31;
  const int stream = wv * 2 + (lane >> 5);   // 0..7
  const int bkv = blockIdx.x & 255;
  const int c   = blockIdx.x >> 8;           // 0..7
  const int b  = bkv >> 3;
  const int kv = bkv & 7;
  const int pos = posp[0];
  const int s0 = c * 256;
  const int dbase = sub * 8;

  // ---- prologue: reduce 24 pqkv chunks for this (b,kv), rope in LDS ----
  {
    const int sec = tid >> 6;                 // 0: q0, 1: q1, 2: k, 3: v
    const int idx = (tid & 63) * 4;
    int nsec;
    if (sec == 0)      nsec = (kv * 2 + 0) * 256;
    else if (sec == 1) nsec = (kv * 2 + 1) * 256;
    else if (sec == 2) nsec = 4096 + kv * 256;
    else               nsec = 6144 + kv * 256;
    const float* pb = pqkv + (size_t)b * 8192 + nsec + idx;
    f32x4 ssum = (f32x4){0.f, 0.f, 0.f, 0.f};
#pragma unroll
    for (int kc = 0; kc < (int)NKC; ++kc) {
      ssum += ld4(pb + (size_t)kc * 262144);   // cached: 8 blocks share via L2
    }
    *(f32x4*)(&accraw[0][sec * 256 + idx]) = ssum;
    __syncthreads();
    f32x4 outv;
    const float* raw = &accraw[0][0];
    if (sec < 3) {
      if (idx < 128) {
        const f32x4 xr = ld4(raw + sec * 256 + idx);
        const f32x4 xi = ld4(raw + sec * 256 + idx + 128);
        const f32x4 cc = ld4(fcos + b * 128 + idx);
        const f32x4 ss = ld4(fsin + b * 128 + idx);
        outv = xr * cc - xi * ss;
      } else {
        const int dd = idx - 128;
        const f32x4 xr = ld4(raw + sec * 256 + dd);
        const f32x4 xi = ld4(raw + sec * 256 + idx);
        const f32x4 cc = ld4(fcos + b * 128 + dd);
        const f32x4 ss = ld4(fsin + b * 128 + dd);
        outv = xr * ss + xi * cc;
      }
      if (sec < 2) outv *= SCALE_;
    } else {
      outv = ld4(raw + 3 * 256 + idx);
    }
    __syncthreads();                 // everyone done reading raw
    *(f32x4*)(&xv[sec][idx]) = outv;
    __syncthreads();
  }

  // ---- main flash loop ----
  const size_t base = ((size_t)b * 8 + kv) * 2048 * 256;
  const float* kbase = cache_k + base;
  const float* vbase = cache_v + base;
  const float* mrow = mask + (size_t)b * 2048;

  const f32x4 qa0 = ld4(&xv[0][dbase]);
  const f32x4 qa1 = ld4(&xv[0][dbase + 4]);
  const f32x4 qb0 = ld4(&xv[1][dbase]);
  const f32x4 qb1 = ld4(&xv[1][dbase + 4]);
  const f32x4 kn0 = ld4(&xv[2][dbase]);
  const f32x4 kn1 = ld4(&xv[2][dbase + 4]);
  const f32x4 vn0 = ld4(&xv[3][dbase]);
  const f32x4 vn1 = ld4(&xv[3][dbase + 4]);

#define LDK(K0, K1, S)                                          \
  { const float* kr_ = kbase + (size_t)(S) * 256;               \
    K0 = ntl4(kr_ + dbase); K1 = ntl4(kr_ + dbase + 4);         \
    if ((S) == pos) { K0 = kn0; K1 = kn1; } }
#define LDV(V0, V1, S)                                          \
  { const float* vr_ = vbase + (size_t)(S) * 256;               \
    V0 = ntl4(vr_ + dbase); V1 = ntl4(vr_ + dbase + 4);         \
    if ((S) == pos) { V0 = vn0; V1 = vn1; } }

  float m0 = -3.4e38f, l0 = 0.f, m1 = -3.4e38f, l1 = 0.f;
  f32x4 a00 = (f32x4){0.f, 0.f, 0.f, 0.f};
  f32x4 a01 = (f32x4){0.f, 0.f, 0.f, 0.f};
  f32x4 a10 = (f32x4){0.f, 0.f, 0.f, 0.f};
  f32x4 a11 = (f32x4){0.f, 0.f, 0.f, 0.f};

  const int sA = s0 + stream;
  const int sB = sA + 8;
  f32x4 kA0, kA1, vA0, vA1, kB0, kB1, vB0, vB1;
  LDK(kA0, kA1, sA); LDV(vA0, vA1, sA);
  float mkA = mrow[sA];
  LDK(kB0, kB1, sB); LDV(vB0, vB1, sB);
  float mkB = mrow[sB];

  for (int i = 0; i < 32; i += 2) {
    {
      float d0 = dot4v(qa0, kA0) + dot4v(qa1, kA1);
      float d1 = dot4v(qb0, kA0) + dot4v(qb1, kA1);
      const int ipf = (i + 2 < 32) ? (i + 2) : 31;
      const int sn = s0 + stream + 8 * ipf;
      LDK(kA0, kA1, sn);
      const float mkn = mrow[sn];
#pragma unroll
      for (int off = 16; off > 0; off >>= 1) {
        d0 += __shfl_xor(d0, off);
        d1 += __shfl_xor(d1, off);
      }
      d0 += mkA; d1 += mkA;
      const float nm0 = fmaxf(m0, d0);
      const float al0 = __expf(m0 - nm0);
      const float p0  = __expf(d0 - nm0);
      m0 = nm0; l0 = fmaf(l0, al0, p0);
      a00 = a00 * al0 + p0 * vA0;
      a01 = a01 * al0 + p0 * vA1;
      const float nm1 = fmaxf(m1, d1);
      const float al1 = __expf(m1 - nm1);
      const float p1  = __expf(d1 - nm1);
      m1 = nm1; l1 = fmaf(l1, al1, p1);
      a10 = a10 * al1 + p1 * vA0;
      a11 = a11 * al1 + p1 * vA1;
      LDV(vA0, vA1, sn);
      mkA = mkn;
    }
    {
      float d0 = dot4v(qa0, kB0) + dot4v(qa1, kB1);
      float d1 = dot4v(qb0, kB0) + dot4v(qb1, kB1);
      const int ipf = (i + 3 < 32) ? (i + 3) : 31;
      const int sn = s0 + stream + 8 * ipf;
      LDK(kB0, kB1, sn);
      const float mkn = mrow[sn];
#pragma unroll
      for (int off = 16; off > 0; off >>= 1) {
        d0 += __shfl_xor(d0, off);
        d1 += __shfl_xor(d1, off);
      }
      d0 += mkB; d1 += mkB;
      const float nm0 = fmaxf(m0, d0);
      const float al0 = __expf(m0 - nm0);
      const float p0  = __expf(d0 - nm0);
      m0 = nm0; l0 = fmaf(l0, al0, p0);
      a00 = a00 * al0 + p0 * vB0;
      a01 = a01 * al0 + p0 * vB1;
      const float nm1 = fmaxf(m1, d1);
      const float al1 = __expf(m1 - nm1);
      const float p1  = __expf(d1 - nm1);
      m1 = nm1; l1 = fmaf(l1, al1, p1);
      a10 = a10 * al1 + p1 * vB0;
      a11 = a11 * al1 + p1 * vB1;
      LDV(vB0, vB1, sn);
      mkB = mkn;
    }
  }
#undef LDK
#undef LDV

  if (sub == 0) {
    mred[stream][0] = m0; mred[stream][1] = l0;
    mred[stream][2] = m1; mred[stream][3] = l1;
  }
  __syncthreads();
  float M0 = -3.4e38f, M1 = -3.4e38f;
#pragma unroll
  for (int t = 0; t < 8; ++t) {
    M0 = fmaxf(M0, mred[t][0]);
    M1 = fmaxf(M1, mred[t][2]);
  }
  const float sc0 = __expf(m0 - M0);
  const float sc1 = __expf(m1 - M1);
  float* ab = &accraw[stream][0];
  ab[dbase + 0] = a00.x * sc0; ab[dbase + 1] = a00.y * sc0;
  ab[dbase + 2] = a00.z * sc0; ab[dbase + 3] = a00.w * sc0;
  ab[dbase + 4] = a01.x * sc0; ab[dbase + 5] = a01.y * sc0;
  ab[dbase + 6] = a01.z * sc0; ab[dbase + 7] = a01.w * sc0;
  ab[256 + dbase + 0] = a10.x * sc1; ab[256 + dbase + 1] = a10.y * sc1;
  ab[256 + dbase + 2] = a10.z * sc1; ab[256 + dbase + 3] = a10.w * sc1;
  ab[256 + dbase + 4] = a11.x * sc1; ab[256 + dbase + 5] = a11.y * sc1;
  ab[256 + dbase + 6] = a11.z * sc1; ab[256 + dbase + 7] = a11.w * sc1;
  __syncthreads();

  if (tid == 0) {
    float L0 = 0.f, L1 = 0.f;
#pragma unroll
    for (int t = 0; t < 8; ++t) {
      L0 = fmaf(mred[t][1], __expf(mred[t][0] - M0), L0);
      L1 = fmaf(mred[t][3], __expf(mred[t][2] - M1), L1);
    }
    float2* mlp = (float2*)ml;
    const int mlbase = ((bkv * 8) + c) * 2;
    mlp[mlbase + 0] = make_float2(M0, L0);
    mlp[mlbase + 1] = make_float2(M1, L1);
  }

  const size_t obase = (size_t)(bkv * 8 + c) * 512;
  for (int t = tid; t < 512; t += 256) {
    float sum = 0.f;
#pragma unroll
    for (int st = 0; st < 8; ++st) sum += accraw[st][t];
    opart[obase + t] = sum;
  }
}

// ---------------------------------------------------------------------------
// Kernel C: fused combine + output projection partials (unchanged logic).
__global__ __launch_bounds__(256) void oproj_fused_kernel(
    const float* __restrict__ opart, const float* __restrict__ ml,
    const float* __restrict__ wo, float* __restrict__ po) {
  __shared__ float xs[32][128];   // 16 KB

  const int t = threadIdx.x;
  const int ctile = blockIdx.x % 24;
  const int rem   = blockIdx.x / 24;
  const int kc    = rem >> 1;            // head 0..15
  const int kh    = rem & 1;             // K-half 0..1 (128 dims)
  const int kvh = kc >> 1, g = kc & 1;

  {
    const int b = t >> 3;
    const int dloc = (t & 7) * 16;
    const int kvb = b * 8 + kvh;
    const float2* mlp = (const float2*)ml;
    float2 mls[8];
    float M = -3.4e38f;
#pragma unroll
    for (int c = 0; c < 8; ++c) {
      mls[c] = mlp[(kvb * 8 + c) * 2 + g];
      M = fmaxf(M, mls[c].x);
    }
    float L = 0.f;
    f32x4 O[4];
#pragma unroll
    for (int q = 0; q < 4; ++q) O[q] = (f32x4){0.f, 0.f, 0.f, 0.f};
#pragma unroll
    for (int c = 0; c < 8; ++c) {
      const float wc = __expf(mls[c].x - M);
      L = fmaf(mls[c].y, wc, L);
      const float* src = opart +
          (size_t)(kvb * 8 + c) * 512 + g * 256 + kh * 128 + dloc;
#pragma unroll
      for (int q = 0; q < 4; ++q) O[q] += wc * ld4(src + q * 4);
    }
    const float invL = 1.f / L;
#pragma unroll
    for (int q = 0; q < 4; ++q) {
      *(f32x4*)(&xs[b][dloc + q * 4]) = O[q] * invL;
    }
  }
  __syncthreads();

  const int lane = t & 31;
  const int half = t >> 5;               // 0..7
  const int n = ctile * 128 + lane * 4;
  const float* wb = wo + (size_t)(kc * 256 + kh * 128) * 3072 + n;

  f32x4 acc[4];
#pragma unroll
  for (int j = 0; j < 4; ++j) acc[j] = (f32x4){0.f, 0.f, 0.f, 0.f};

  f32x4 wA[4], wB[4];
#define LDW(S, KK)                                                 \
  {                                                                \
    S[0] = ntl4(wb + (size_t)((KK) + 0) * 3072);                   \
    S[1] = ntl4(wb + (size_t)((KK) + 1) * 3072);                   \
    S[2] = ntl4(wb + (size_t)((KK) + 2) * 3072);                   \
    S[3] = ntl4(wb + (size_t)((KK) + 3) * 3072);                   \
  }
#define CMP(S, KK)                                                 \
  {                                                                \
    _Pragma("unroll")                                              \
    for (int j = 0; j < 4; ++j) {                                  \
      const f32x4 xv = *(const f32x4*)(&xs[half * 4 + j][(KK)]);   \
      acc[j] += xv.x * S[0];                                       \
      acc[j] += xv.y * S[1];                                       \
      acc[j] += xv.z * S[2];                                       \
      acc[j] += xv.w * S[3];                                       \
    }                                                              \
  }

  LDW(wA, 0);
  for (int k = 0; k < 128; k += 8) {
    LDW(wB, k + 4);
    CMP(wA, k);
    const int kn = (k + 8 < 128) ? (k + 8) : 0;
    LDW(wA, kn);
    CMP(wB, k + 4);
  }
#undef LDW
#undef CMP

#pragma unroll
  for (int j = 0; j < 4; ++j) {
    *(f32x4*)(po + ((size_t)(kc * 2 + kh) * 32 + half * 4 + j) * 3072 + n)
        = acc[j];
  }
}

// ---------------------------------------------------------------------------
// Kernel D: sum the 32 out-proj partials -> d_out.
__global__ __launch_bounds__(256) void finalize_kernel(
    const float* __restrict__ po, float* __restrict__ out) {
  const int i = blockIdx.x * 256 + threadIdx.x;  // < 24576 float4s
  f32x4 acc = (f32x4){0.f, 0.f, 0.f, 0.f};
#pragma unroll
  for (int kc = 0; kc < 32; ++kc) {
    acc += ntl4(po + ((size_t)kc * 24576 + i) * 4);
  }
  *(f32x4*)((float*)out + (size_t)i * 4) = acc;
}

// ---------------------------------------------------------------------------
extern "C" void kernel_launch(void* const* d_in, const int* in_sizes, int n_in,
                              void* d_out, int out_size, void* d_ws, size_t ws_size,
                              hipStream_t stream) {
  (void)in_sizes; (void)n_in; (void)out_size; (void)ws_size;
  const float* x    = (const float*)d_in[0];
  const float* fcos = (const float*)d_in[1];
  const float* fsin = (const float*)d_in[2];
  const float* mask = (const float*)d_in[3];
  const float* ck   = (const float*)d_in[4];
  const float* cv   = (const float*)d_in[5];
  const float* wq   = (const float*)d_in[6];
  const float* wk   = (const float*)d_in[7];
  const float* wv   = (const float*)d_in[8];
  const float* wo   = (const float*)d_in[9];
  const int*   pos  = (const int*)d_in[10];

  float* ws    = (float*)d_ws;
  float* pqkv  = ws;
  float* po    = ws + OFF_PO;
  float* opart = ws + OFF_OPART;
  float* ml    = ws + OFF_ML;
  float* out   = (float*)d_out;

  qkv_partial_kernel<<<768, 512, 0, stream>>>(x, wq, wk, wv, pqkv);
  attn_fused_kernel<<<2048, 256, 0, stream>>>(pqkv, fcos, fsin, ck, cv, mask,
                                              pos, opart, ml);
  oproj_fused_kernel<<<768, 256, 0, stream>>>(opart, ml, wo, po);
  finalize_kernel<<<96, 256, 0, stream>>>(po, out);
}

// Round 11
// 320.213 us; speedup vs baseline: 1.0487x; 1.0487x over previous
//
#include <hip/hip_runtime.h>
#include <hip/hip_bf16.h>

// Gemma attention decode: B=32, L=1, HID=3072, H=16, KV=8, D=256, S=2048
// All fp32. Memory-bound. Ledger: attn~180-185us (92% of BW floor),
// small kernels ~66us (~their cold floor), ~50us kernel-boundary overhead.
// R11: revert R10's rope fusion (cost +31us redundant traffic); R9 structure
// with qkv at 512 threads/block (24 waves/CU for the weight stream).

#define SCALE_ 0.0625f   // D^-0.5 = 1/16

#define NKC   24u
#define OFF_XQKV (NKC*32u*8192u)           // 6291456
#define OFF_PO   (OFF_XQKV + 262144u)      // 6553600
#define OFF_ML   (1048576u)

typedef float f32x4 __attribute__((ext_vector_type(4)));

__device__ inline f32x4 ntl4(const float* p) {
  return __builtin_nontemporal_load((const f32x4*)p);
}
__device__ inline void nts4(float* p, f32x4 v) {
  __builtin_nontemporal_store(v, (f32x4*)p);
}
__device__ inline f32x4 ld4(const float* p) { return *(const f32x4*)p; }

__device__ inline float dot4v(f32x4 a, f32x4 b) {
  return a.x * b.x + a.y * b.y + a.z * b.z + a.w * b.w;
}

// ---------------------------------------------------------------------------
// Kernel A: QKV projection, split-K partials.
// grid = 32 ctiles x 24 K-chunks = 768 blocks; block = 512 thr (8 waves).
// Weights NT (single-use); each weight byte fetched once across the grid.
__global__ __launch_bounds__(512) void qkv_partial_kernel(
    const float* __restrict__ x, const float* __restrict__ wq,
    const float* __restrict__ wk, const float* __restrict__ wv,
    float* __restrict__ pqkv) {
  __shared__ float xls[32][128];            // 16 KB

  const int lane = threadIdx.x & 63;
  const int bg   = threadIdx.x >> 6;        // 0..7 -> batches bg*4..bg*4+3
  const int ctile = blockIdx.x & 31;
  const int kc    = blockIdx.x >> 5;        // 0..23
  const int n = ctile * 256 + lane * 4;

  for (int i = threadIdx.x; i < 1024; i += 512) {
    const int b = i >> 5;
    const int r = i & 31;
    *(f32x4*)(&xls[b][r * 4]) = ld4(x + (size_t)b * 3072 + kc * 128 + r * 4);
  }

  const float* w; int stride, nn;
  if (n < 4096)      { w = wq; stride = 4096; nn = n; }
  else if (n < 6144) { w = wk; stride = 2048; nn = n - 4096; }
  else               { w = wv; stride = 2048; nn = n - 6144; }
  const float* wb = w + (size_t)(kc * 128) * stride + nn;

  f32x4 acc[4];
#pragma unroll
  for (int j = 0; j < 4; ++j) acc[j] = (f32x4){0.f, 0.f, 0.f, 0.f};

  __syncthreads();

  f32x4 wA[4], wB[4];
#define LDW(S, KK)                                                   \
  {                                                                  \
    S[0] = ntl4(wb + (size_t)((KK) + 0) * stride);                   \
    S[1] = ntl4(wb + (size_t)((KK) + 1) * stride);                   \
    S[2] = ntl4(wb + (size_t)((KK) + 2) * stride);                   \
    S[3] = ntl4(wb + (size_t)((KK) + 3) * stride);                   \
  }
#define CMP(S, KK)                                                   \
  {                                                                  \
    _Pragma("unroll")                                                \
    for (int j = 0; j < 4; ++j) {                                    \
      const f32x4 xv = *(const f32x4*)(&xls[bg * 4 + j][(KK)]);      \
      acc[j] += xv.x * S[0];                                         \
      acc[j] += xv.y * S[1];                                         \
      acc[j] += xv.z * S[2];                                         \
      acc[j] += xv.w * S[3];                                         \
    }                                                                \
  }

  LDW(wA, 0);
  for (int k = 0; k < 128; k += 8) {
    LDW(wB, k + 4);
    CMP(wA, k);
    const int kn = (k + 8 < 128) ? (k + 8) : 0;
    LDW(wA, kn);
    CMP(wB, k + 4);
  }
#undef LDW
#undef CMP

#pragma unroll
  for (int j = 0; j < 4; ++j) {
    nts4(pqkv + ((size_t)kc * 32 + bg * 4 + j) * 8192 + n, acc[j]);
  }
}

// ---------------------------------------------------------------------------
// Kernel B: reduce 24 split-K partials + RoPE. pqkv: NT loads (single-use).
__global__ __launch_bounds__(256) void reduce_rope_kernel(
    const float* __restrict__ pqkv, const float* __restrict__ fcos,
    const float* __restrict__ fsin, float* __restrict__ xqkv) {
  const int w = blockIdx.x * 256 + threadIdx.x;   // < 40960
  const int b = w / 1280;
  const int r = w - b * 1280;
  const float* pb = pqkv + (size_t)b * 8192;
  float* ob = xqkv + (size_t)b * 8192;

  if (r < 768) {
    int n1, d;
    const bool isq = (r < 512);
    if (isq) { const int h = r >> 5; d = (r & 31) * 4; n1 = h * 256 + d; }
    else     { const int p = r - 512; const int kvh = p >> 5; d = (p & 31) * 4;
               n1 = 4096 + kvh * 256 + d; }
    const int n2 = n1 + 128;
    f32x4 xr = (f32x4){0.f, 0.f, 0.f, 0.f};
    f32x4 xi = (f32x4){0.f, 0.f, 0.f, 0.f};
    for (int kc = 0; kc < (int)NKC; ++kc) {
      xr += ntl4(pb + (size_t)kc * 262144 + n1);
      xi += ntl4(pb + (size_t)kc * 262144 + n2);
    }
    const f32x4 c = ld4(fcos + b * 128 + d);
    const f32x4 s = ld4(fsin + b * 128 + d);
    f32x4 o1 = xr * c - xi * s;
    f32x4 o2 = xr * s + xi * c;
    if (isq) { o1 *= SCALE_; o2 *= SCALE_; }
    *(f32x4*)(ob + n1) = o1;
    *(f32x4*)(ob + n2) = o2;
  } else {
    const int nn = 6144 + (r - 768) * 4;
    f32x4 v = (f32x4){0.f, 0.f, 0.f, 0.f};
    for (int kc = 0; kc < (int)NKC; ++kc) {
      v += ntl4(pb + (size_t)kc * 262144 + nn);
    }
    *(f32x4*)(ob + nn) = v;
  }
}

// ---------------------------------------------------------------------------
// Kernel C: flash-decode attention chunk. K/V: NT loads (pure stream).
__global__ __launch_bounds__(256) void attn_chunk_kernel(
    const float* __restrict__ xqkv, const float* __restrict__ cache_k,
    const float* __restrict__ cache_v, const float* __restrict__ mask,
    const int* __restrict__ posp, float* __restrict__ opart,
    float* __restrict__ ml) {
  __shared__ float accbuf[8][512];   // per stream: [g*256+d], 16 KB
  __shared__ float mred[8][4];       // per stream: m0,l0,m1,l1

  const int tid = threadIdx.x, lane = tid & 63, wv = tid >> 6;
  const int sub = lane & 31;
  const int stream = wv * 2 + (lane >> 5);   // 0..7
  const int c  = blockIdx.x & 7;
  const int kv = (blockIdx.x >> 3) & 7;
  const int b  = blockIdx.x >> 6;
  const int pos = posp[0];
  const int s0 = c * 256;
  const int dbase = sub * 8;

  const float* xb = xqkv + (size_t)b * 8192;
  const float* knew = xb + 4096 + kv * 256;
  const float* vnew = xb + 6144 + kv * 256;
  const size_t base = ((size_t)b * 8 + kv) * 2048 * 256;
  const float* kbase = cache_k + base;
  const float* vbase = cache_v + base;
  const float* mrow = mask + (size_t)b * 2048;

  const f32x4 qa0 = ld4(xb + (kv * 2 + 0) * 256 + dbase);
  const f32x4 qa1 = ld4(xb + (kv * 2 + 0) * 256 + dbase + 4);
  const f32x4 qb0 = ld4(xb + (kv * 2 + 1) * 256 + dbase);
  const f32x4 qb1 = ld4(xb + (kv * 2 + 1) * 256 + dbase + 4);

  float m0 = -3.4e38f, l0 = 0.f, m1 = -3.4e38f, l1 = 0.f;
  f32x4 a00 = (f32x4){0.f, 0.f, 0.f, 0.f};
  f32x4 a01 = (f32x4){0.f, 0.f, 0.f, 0.f};
  f32x4 a10 = (f32x4){0.f, 0.f, 0.f, 0.f};
  f32x4 a11 = (f32x4){0.f, 0.f, 0.f, 0.f};

  int sA = s0 + stream;
  int sB = sA + 8;
  const float* krA = (sA == pos) ? knew : (kbase + (size_t)sA * 256);
  const float* vrA = (sA == pos) ? vnew : (vbase + (size_t)sA * 256);
  const float* krB = (sB == pos) ? knew : (kbase + (size_t)sB * 256);
  const float* vrB = (sB == pos) ? vnew : (vbase + (size_t)sB * 256);
  f32x4 kA0 = ntl4(krA + dbase);
  f32x4 kA1 = ntl4(krA + dbase + 4);
  f32x4 vA0 = ntl4(vrA + dbase);
  f32x4 vA1 = ntl4(vrA + dbase + 4);
  float mkA = mrow[sA];
  f32x4 kB0 = ntl4(krB + dbase);
  f32x4 kB1 = ntl4(krB + dbase + 4);
  f32x4 vB0 = ntl4(vrB + dbase);
  f32x4 vB1 = ntl4(vrB + dbase + 4);
  float mkB = mrow[sB];

  for (int i = 0; i < 32; i += 2) {
    {
      float d0 = dot4v(qa0, kA0) + dot4v(qa1, kA1);
      float d1 = dot4v(qb0, kA0) + dot4v(qb1, kA1);
      const int ipf = (i + 2 < 32) ? (i + 2) : 31;
      const int sn = s0 + stream + 8 * ipf;
      const float* krn = (sn == pos) ? knew : (kbase + (size_t)sn * 256);
      const float* vrn = (sn == pos) ? vnew : (vbase + (size_t)sn * 256);
      kA0 = ntl4(krn + dbase);
      kA1 = ntl4(krn + dbase + 4);
      const float mkn = mrow[sn];
#pragma unroll
      for (int off = 16; off > 0; off >>= 1) {
        d0 += __shfl_xor(d0, off);
        d1 += __shfl_xor(d1, off);
      }
      d0 += mkA; d1 += mkA;
      const float nm0 = fmaxf(m0, d0);
      const float al0 = __expf(m0 - nm0);
      const float p0  = __expf(d0 - nm0);
      m0 = nm0; l0 = fmaf(l0, al0, p0);
      a00 = a00 * al0 + p0 * vA0;
      a01 = a01 * al0 + p0 * vA1;
      const float nm1 = fmaxf(m1, d1);
      const float al1 = __expf(m1 - nm1);
      const float p1  = __expf(d1 - nm1);
      m1 = nm1; l1 = fmaf(l1, al1, p1);
      a10 = a10 * al1 + p1 * vA0;
      a11 = a11 * al1 + p1 * vA1;
      vA0 = ntl4(vrn + dbase);
      vA1 = ntl4(vrn + dbase + 4);
      mkA = mkn;
    }
    {
      float d0 = dot4v(qa0, kB0) + dot4v(qa1, kB1);
      float d1 = dot4v(qb0, kB0) + dot4v(qb1, kB1);
      const int ipf = (i + 3 < 32) ? (i + 3) : 31;
      const int sn = s0 + stream + 8 * ipf;
      const float* krn = (sn == pos) ? knew : (kbase + (size_t)sn * 256);
      const float* vrn = (sn == pos) ? vnew : (vbase + (size_t)sn * 256);
      kB0 = ntl4(krn + dbase);
      kB1 = ntl4(krn + dbase + 4);
      const float mkn = mrow[sn];
#pragma unroll
      for (int off = 16; off > 0; off >>= 1) {
        d0 += __shfl_xor(d0, off);
        d1 += __shfl_xor(d1, off);
      }
      d0 += mkB; d1 += mkB;
      const float nm0 = fmaxf(m0, d0);
      const float al0 = __expf(m0 - nm0);
      const float p0  = __expf(d0 - nm0);
      m0 = nm0; l0 = fmaf(l0, al0, p0);
      a00 = a00 * al0 + p0 * vB0;
      a01 = a01 * al0 + p0 * vB1;
      const float nm1 = fmaxf(m1, d1);
      const float al1 = __expf(m1 - nm1);
      const float p1  = __expf(d1 - nm1);
      m1 = nm1; l1 = fmaf(l1, al1, p1);
      a10 = a10 * al1 + p1 * vB0;
      a11 = a11 * al1 + p1 * vB1;
      vB0 = ntl4(vrn + dbase);
      vB1 = ntl4(vrn + dbase + 4);
      mkB = mkn;
    }
  }

  if (sub == 0) {
    mred[stream][0] = m0; mred[stream][1] = l0;
    mred[stream][2] = m1; mred[stream][3] = l1;
  }
  __syncthreads();
  float M0 = -3.4e38f, M1 = -3.4e38f;
#pragma unroll
  for (int t = 0; t < 8; ++t) {
    M0 = fmaxf(M0, mred[t][0]);
    M1 = fmaxf(M1, mred[t][2]);
  }
  const float sc0 = __expf(m0 - M0);
  const float sc1 = __expf(m1 - M1);
  float* ab = &accbuf[stream][0];
  ab[dbase + 0] = a00.x * sc0; ab[dbase + 1] = a00.y * sc0;
  ab[dbase + 2] = a00.z * sc0; ab[dbase + 3] = a00.w * sc0;
  ab[dbase + 4] = a01.x * sc0; ab[dbase + 5] = a01.y * sc0;
  ab[dbase + 6] = a01.z * sc0; ab[dbase + 7] = a01.w * sc0;
  ab[256 + dbase + 0] = a10.x * sc1; ab[256 + dbase + 1] = a10.y * sc1;
  ab[256 + dbase + 2] = a10.z * sc1; ab[256 + dbase + 3] = a10.w * sc1;
  ab[256 + dbase + 4] = a11.x * sc1; ab[256 + dbase + 5] = a11.y * sc1;
  ab[256 + dbase + 6] = a11.z * sc1; ab[256 + dbase + 7] = a11.w * sc1;
  __syncthreads();

  if (tid == 0) {
    float L0 = 0.f, L1 = 0.f;
#pragma unroll
    for (int t = 0; t < 8; ++t) {
      L0 = fmaf(mred[t][1], __expf(mred[t][0] - M0), L0);
      L1 = fmaf(mred[t][3], __expf(mred[t][2] - M1), L1);
    }
    float2* mlp = (float2*)ml;
    const int mlbase = (((b * 8 + kv) * 8) + c) * 2;
    mlp[mlbase + 0] = make_float2(M0, L0);
    mlp[mlbase + 1] = make_float2(M1, L1);
  }

  const size_t obase = (size_t)((b * 8 + kv) * 8 + c) * 512;
  for (int t = tid; t < 512; t += 256) {
    float sum = 0.f;
#pragma unroll
    for (int st = 0; st < 8; ++st) sum += accbuf[st][t];
    opart[obase + t] = sum;     // cached: oproj re-reads heavily
  }
}

// ---------------------------------------------------------------------------
// Kernel D: fused combine + output projection partials. wo: NT loads.
__global__ __launch_bounds__(256) void oproj_fused_kernel(
    const float* __restrict__ opart, const float* __restrict__ ml,
    const float* __restrict__ wo, float* __restrict__ po) {
  __shared__ float xs[32][128];   // 16 KB

  const int t = threadIdx.x;
  const int ctile = blockIdx.x % 24;
  const int rem   = blockIdx.x / 24;
  const int kc    = rem >> 1;            // head 0..15
  const int kh    = rem & 1;             // K-half 0..1 (128 dims)
  const int kvh = kc >> 1, g = kc & 1;

  {
    const int b = t >> 3;
    const int dloc = (t & 7) * 16;
    const int kvb = b * 8 + kvh;
    const float2* mlp = (const float2*)ml;
    float2 mls[8];
    float M = -3.4e38f;
#pragma unroll
    for (int c = 0; c < 8; ++c) {
      mls[c] = mlp[(kvb * 8 + c) * 2 + g];
      M = fmaxf(M, mls[c].x);
    }
    float L = 0.f;
    f32x4 O[4];
#pragma unroll
    for (int q = 0; q < 4; ++q) O[q] = (f32x4){0.f, 0.f, 0.f, 0.f};
#pragma unroll
    for (int c = 0; c < 8; ++c) {
      const float wc = __expf(mls[c].x - M);
      L = fmaf(mls[c].y, wc, L);
      const float* src = opart +
          (size_t)(kvb * 8 + c) * 512 + g * 256 + kh * 128 + dloc;
#pragma unroll
      for (int q = 0; q < 4; ++q) O[q] += wc * ld4(src + q * 4);
    }
    const float invL = 1.f / L;
#pragma unroll
    for (int q = 0; q < 4; ++q) {
      *(f32x4*)(&xs[b][dloc + q * 4]) = O[q] * invL;
    }
  }
  __syncthreads();

  const int lane = t & 31;
  const int half = t >> 5;               // 0..7
  const int n = ctile * 128 + lane * 4;
  const float* wb = wo + (size_t)(kc * 256 + kh * 128) * 3072 + n;

  f32x4 acc[4];
#pragma unroll
  for (int j = 0; j < 4; ++j) acc[j] = (f32x4){0.f, 0.f, 0.f, 0.f};

  f32x4 wA[4], wB[4];
#define LDW(S, KK)                                                 \
  {                                                                \
    S[0] = ntl4(wb + (size_t)((KK) + 0) * 3072);                   \
    S[1] = ntl4(wb + (size_t)((KK) + 1) * 3072);                   \
    S[2] = ntl4(wb + (size_t)((KK) + 2) * 3072);                   \
    S[3] = ntl4(wb + (size_t)((KK) + 3) * 3072);                   \
  }
#define CMP(S, KK)                                                 \
  {                                                                \
    _Pragma("unroll")                                              \
    for (int j = 0; j < 4; ++j) {                                  \
      const f32x4 xv = *(const f32x4*)(&xs[half * 4 + j][(KK)]);   \
      acc[j] += xv.x * S[0];                                       \
      acc[j] += xv.y * S[1];                                       \
      acc[j] += xv.z * S[2];                                       \
      acc[j] += xv.w * S[3];                                       \
    }                                                              \
  }

  LDW(wA, 0);
  for (int k = 0; k < 128; k += 8) {
    LDW(wB, k + 4);
    CMP(wA, k);
    const int kn = (k + 8 < 128) ? (k + 8) : 0;
    LDW(wA, kn);
    CMP(wB, k + 4);
  }
#undef LDW
#undef CMP

#pragma unroll
  for (int j = 0; j < 4; ++j) {
    *(f32x4*)(po + ((size_t)(kc * 2 + kh) * 32 + half * 4 + j) * 3072 + n)
        = acc[j];
  }
}

// ---------------------------------------------------------------------------
// Kernel E: sum the 32 out-proj partials -> d_out. po: NT loads.
__global__ __launch_bounds__(256) void finalize_kernel(
    const float* __restrict__ po, float* __restrict__ out) {
  const int i = blockIdx.x * 256 + threadIdx.x;  // < 24576 float4s
  f32x4 acc = (f32x4){0.f, 0.f, 0.f, 0.f};
#pragma unroll
  for (int kc = 0; kc < 32; ++kc) {
    acc += ntl4(po + ((size_t)kc * 24576 + i) * 4);
  }
  *(f32x4*)((float*)out + (size_t)i * 4) = acc;
}

// ---------------------------------------------------------------------------
extern "C" void kernel_launch(void* const* d_in, const int* in_sizes, int n_in,
                              void* d_out, int out_size, void* d_ws, size_t ws_size,
                              hipStream_t stream) {
  (void)in_sizes; (void)n_in; (void)out_size; (void)ws_size;
  const float* x    = (const float*)d_in[0];
  const float* fcos = (const float*)d_in[1];
  const float* fsin = (const float*)d_in[2];
  const float* mask = (const float*)d_in[3];
  const float* ck   = (const float*)d_in[4];
  const float* cv   = (const float*)d_in[5];
  const float* wq   = (const float*)d_in[6];
  const float* wk   = (const float*)d_in[7];
  const float* wv   = (const float*)d_in[8];
  const float* wo   = (const float*)d_in[9];
  const int*   pos  = (const int*)d_in[10];

  float* ws    = (float*)d_ws;
  float* pqkv  = ws;                 // dead after reduce_rope
  float* opart = ws;                 // aliases pqkv (used after it's dead)
  float* ml    = ws + OFF_ML;
  float* xqkv  = ws + OFF_XQKV;
  float* po    = ws + OFF_PO;
  float* out   = (float*)d_out;

  qkv_partial_kernel<<<768, 512, 0, stream>>>(x, wq, wk, wv, pqkv);
  reduce_rope_kernel<<<160, 256, 0, stream>>>(pqkv, fcos, fsin, xqkv);
  attn_chunk_kernel<<<2048, 256, 0, stream>>>(xqkv, ck, cv, mask, pos, opart, ml);
  oproj_fused_kernel<<<768, 256, 0, stream>>>(opart, ml, wo, po);
  finalize_kernel<<<96, 256, 0, stream>>>(po, out);
}

// Round 12
// 305.256 us; speedup vs baseline: 1.1001x; 1.0490x over previous
//
#include <hip/hip_runtime.h>
#include <hip/hip_bf16.h>

// Gemma attention decode: B=32, L=1, HID=3072, H=16, KV=8, D=256, S=2048
// All fp32. Memory-bound. Best measured config (R9): 304.8us.
// R12 = exact revert to R9 (R11's qkv 512-thr change regressed +15us).
// Ledger: attn~185us (92% of BW floor), small kernels ~66us (~cold floor),
// ~50us kernel-boundary overhead (R6/R8 double-launch diagnostics).

#define SCALE_ 0.0625f   // D^-0.5 = 1/16

#define NKC   24u
#define OFF_XQKV (NKC*32u*8192u)           // 6291456
#define OFF_PO   (OFF_XQKV + 262144u)      // 6553600
#define OFF_ML   (1048576u)

typedef float f32x4 __attribute__((ext_vector_type(4)));

__device__ inline f32x4 ntl4(const float* p) {
  return __builtin_nontemporal_load((const f32x4*)p);
}
__device__ inline void nts4(float* p, f32x4 v) {
  __builtin_nontemporal_store(v, (f32x4*)p);
}
__device__ inline f32x4 ld4(const float* p) { return *(const f32x4*)p; }

__device__ inline float dot4v(f32x4 a, f32x4 b) {
  return a.x * b.x + a.y * b.y + a.z * b.z + a.w * b.w;
}

// ---------------------------------------------------------------------------
// Kernel A: QKV projection, split-K partials. grid = 32 ctiles x 24 K-chunks,
// block = 256 thr: lane -> 4 cols, bg(4) -> 8 batches. Weights NT, read once.
__global__ __launch_bounds__(256) void qkv_partial_kernel(
    const float* __restrict__ x, const float* __restrict__ wq,
    const float* __restrict__ wk, const float* __restrict__ wv,
    float* __restrict__ pqkv) {
  __shared__ float xls[32][128];            // 16 KB

  const int lane = threadIdx.x & 63;
  const int bg   = threadIdx.x >> 6;        // 0..3 -> batches bg*8..bg*8+7
  const int ctile = blockIdx.x & 31;
  const int kc    = blockIdx.x >> 5;        // 0..23
  const int n = ctile * 256 + lane * 4;

  for (int i = threadIdx.x; i < 1024; i += 256) {
    const int b = i >> 5;
    const int r = i & 31;
    *(f32x4*)(&xls[b][r * 4]) = ld4(x + (size_t)b * 3072 + kc * 128 + r * 4);
  }

  const float* w; int stride, nn;
  if (n < 4096)      { w = wq; stride = 4096; nn = n; }
  else if (n < 6144) { w = wk; stride = 2048; nn = n - 4096; }
  else               { w = wv; stride = 2048; nn = n - 6144; }
  const float* wb = w + (size_t)(kc * 128) * stride + nn;

  f32x4 acc[8];
#pragma unroll
  for (int j = 0; j < 8; ++j) acc[j] = (f32x4){0.f, 0.f, 0.f, 0.f};

  __syncthreads();

  f32x4 wA[4], wB[4];
#define LDW(S, KK)                                                   \
  {                                                                  \
    S[0] = ntl4(wb + (size_t)((KK) + 0) * stride);                   \
    S[1] = ntl4(wb + (size_t)((KK) + 1) * stride);                   \
    S[2] = ntl4(wb + (size_t)((KK) + 2) * stride);                   \
    S[3] = ntl4(wb + (size_t)((KK) + 3) * stride);                   \
  }
#define CMP(S, KK)                                                   \
  {                                                                  \
    _Pragma("unroll")                                                \
    for (int j = 0; j < 8; ++j) {                                    \
      const f32x4 xv = *(const f32x4*)(&xls[bg * 8 + j][(KK)]);      \
      acc[j] += xv.x * S[0];                                         \
      acc[j] += xv.y * S[1];                                         \
      acc[j] += xv.z * S[2];                                         \
      acc[j] += xv.w * S[3];                                         \
    }                                                                \
  }

  LDW(wA, 0);
  for (int k = 0; k < 128; k += 8) {
    LDW(wB, k + 4);
    CMP(wA, k);
    const int kn = (k + 8 < 128) ? (k + 8) : 0;
    LDW(wA, kn);
    CMP(wB, k + 4);
  }
#undef LDW
#undef CMP

#pragma unroll
  for (int j = 0; j < 8; ++j) {
    nts4(pqkv + ((size_t)kc * 32 + bg * 8 + j) * 8192 + n, acc[j]);
  }
}

// ---------------------------------------------------------------------------
// Kernel B: reduce 24 split-K partials + RoPE. pqkv: NT loads (single-use).
__global__ __launch_bounds__(256) void reduce_rope_kernel(
    const float* __restrict__ pqkv, const float* __restrict__ fcos,
    const float* __restrict__ fsin, float* __restrict__ xqkv) {
  const int w = blockIdx.x * 256 + threadIdx.x;   // < 40960
  const int b = w / 1280;
  const int r = w - b * 1280;
  const float* pb = pqkv + (size_t)b * 8192;
  float* ob = xqkv + (size_t)b * 8192;

  if (r < 768) {
    int n1, d;
    const bool isq = (r < 512);
    if (isq) { const int h = r >> 5; d = (r & 31) * 4; n1 = h * 256 + d; }
    else     { const int p = r - 512; const int kvh = p >> 5; d = (p & 31) * 4;
               n1 = 4096 + kvh * 256 + d; }
    const int n2 = n1 + 128;
    f32x4 xr = (f32x4){0.f, 0.f, 0.f, 0.f};
    f32x4 xi = (f32x4){0.f, 0.f, 0.f, 0.f};
    for (int kc = 0; kc < (int)NKC; ++kc) {
      xr += ntl4(pb + (size_t)kc * 262144 + n1);
      xi += ntl4(pb + (size_t)kc * 262144 + n2);
    }
    const f32x4 c = ld4(fcos + b * 128 + d);
    const f32x4 s = ld4(fsin + b * 128 + d);
    f32x4 o1 = xr * c - xi * s;
    f32x4 o2 = xr * s + xi * c;
    if (isq) { o1 *= SCALE_; o2 *= SCALE_; }
    *(f32x4*)(ob + n1) = o1;
    *(f32x4*)(ob + n2) = o2;
  } else {
    const int nn = 6144 + (r - 768) * 4;
    f32x4 v = (f32x4){0.f, 0.f, 0.f, 0.f};
    for (int kc = 0; kc < (int)NKC; ++kc) {
      v += ntl4(pb + (size_t)kc * 262144 + nn);
    }
    *(f32x4*)(ob + nn) = v;
  }
}

// ---------------------------------------------------------------------------
// Kernel C: flash-decode attention chunk. K/V: NT loads (pure stream).
__global__ __launch_bounds__(256) void attn_chunk_kernel(
    const float* __restrict__ xqkv, const float* __restrict__ cache_k,
    const float* __restrict__ cache_v, const float* __restrict__ mask,
    const int* __restrict__ posp, float* __restrict__ opart,
    float* __restrict__ ml) {
  __shared__ float accbuf[8][512];   // per stream: [g*256+d], 16 KB
  __shared__ float mred[8][4];       // per stream: m0,l0,m1,l1

  const int tid = threadIdx.x, lane = tid & 63, wv = tid >> 6;
  const int sub = lane & 31;
  const int stream = wv * 2 + (lane >> 5);   // 0..7
  const int c  = blockIdx.x & 7;
  const int kv = (blockIdx.x >> 3) & 7;
  const int b  = blockIdx.x >> 6;
  const int pos = posp[0];
  const int s0 = c * 256;
  const int dbase = sub * 8;

  const float* xb = xqkv + (size_t)b * 8192;
  const float* knew = xb + 4096 + kv * 256;
  const float* vnew = xb + 6144 + kv * 256;
  const size_t base = ((size_t)b * 8 + kv) * 2048 * 256;
  const float* kbase = cache_k + base;
  const float* vbase = cache_v + base;
  const float* mrow = mask + (size_t)b * 2048;

  const f32x4 qa0 = ld4(xb + (kv * 2 + 0) * 256 + dbase);
  const f32x4 qa1 = ld4(xb + (kv * 2 + 0) * 256 + dbase + 4);
  const f32x4 qb0 = ld4(xb + (kv * 2 + 1) * 256 + dbase);
  const f32x4 qb1 = ld4(xb + (kv * 2 + 1) * 256 + dbase + 4);

  float m0 = -3.4e38f, l0 = 0.f, m1 = -3.4e38f, l1 = 0.f;
  f32x4 a00 = (f32x4){0.f, 0.f, 0.f, 0.f};
  f32x4 a01 = (f32x4){0.f, 0.f, 0.f, 0.f};
  f32x4 a10 = (f32x4){0.f, 0.f, 0.f, 0.f};
  f32x4 a11 = (f32x4){0.f, 0.f, 0.f, 0.f};

  int sA = s0 + stream;
  int sB = sA + 8;
  const float* krA = (sA == pos) ? knew : (kbase + (size_t)sA * 256);
  const float* vrA = (sA == pos) ? vnew : (vbase + (size_t)sA * 256);
  const float* krB = (sB == pos) ? knew : (kbase + (size_t)sB * 256);
  const float* vrB = (sB == pos) ? vnew : (vbase + (size_t)sB * 256);
  f32x4 kA0 = ntl4(krA + dbase);
  f32x4 kA1 = ntl4(krA + dbase + 4);
  f32x4 vA0 = ntl4(vrA + dbase);
  f32x4 vA1 = ntl4(vrA + dbase + 4);
  float mkA = mrow[sA];
  f32x4 kB0 = ntl4(krB + dbase);
  f32x4 kB1 = ntl4(krB + dbase + 4);
  f32x4 vB0 = ntl4(vrB + dbase);
  f32x4 vB1 = ntl4(vrB + dbase + 4);
  float mkB = mrow[sB];

  for (int i = 0; i < 32; i += 2) {
    {
      float d0 = dot4v(qa0, kA0) + dot4v(qa1, kA1);
      float d1 = dot4v(qb0, kA0) + dot4v(qb1, kA1);
      const int ipf = (i + 2 < 32) ? (i + 2) : 31;
      const int sn = s0 + stream + 8 * ipf;
      const float* krn = (sn == pos) ? knew : (kbase + (size_t)sn * 256);
      const float* vrn = (sn == pos) ? vnew : (vbase + (size_t)sn * 256);
      kA0 = ntl4(krn + dbase);
      kA1 = ntl4(krn + dbase + 4);
      const float mkn = mrow[sn];
#pragma unroll
      for (int off = 16; off > 0; off >>= 1) {
        d0 += __shfl_xor(d0, off);
        d1 += __shfl_xor(d1, off);
      }
      d0 += mkA; d1 += mkA;
      const float nm0 = fmaxf(m0, d0);
      const float al0 = __expf(m0 - nm0);
      const float p0  = __expf(d0 - nm0);
      m0 = nm0; l0 = fmaf(l0, al0, p0);
      a00 = a00 * al0 + p0 * vA0;
      a01 = a01 * al0 + p0 * vA1;
      const float nm1 = fmaxf(m1, d1);
      const float al1 = __expf(m1 - nm1);
      const float p1  = __expf(d1 - nm1);
      m1 = nm1; l1 = fmaf(l1, al1, p1);
      a10 = a10 * al1 + p1 * vA0;
      a11 = a11 * al1 + p1 * vA1;
      vA0 = ntl4(vrn + dbase);
      vA1 = ntl4(vrn + dbase + 4);
      mkA = mkn;
    }
    {
      float d0 = dot4v(qa0, kB0) + dot4v(qa1, kB1);
      float d1 = dot4v(qb0, kB0) + dot4v(qb1, kB1);
      const int ipf = (i + 3 < 32) ? (i + 3) : 31;
      const int sn = s0 + stream + 8 * ipf;
      const float* krn = (sn == pos) ? knew : (kbase + (size_t)sn * 256);
      const float* vrn = (sn == pos) ? vnew : (vbase + (size_t)sn * 256);
      kB0 = ntl4(krn + dbase);
      kB1 = ntl4(krn + dbase + 4);
      const float mkn = mrow[sn];
#pragma unroll
      for (int off = 16; off > 0; off >>= 1) {
        d0 += __shfl_xor(d0, off);
        d1 += __shfl_xor(d1, off);
      }
      d0 += mkB; d1 += mkB;
      const float nm0 = fmaxf(m0, d0);
      const float al0 = __expf(m0 - nm0);
      const float p0  = __expf(d0 - nm0);
      m0 = nm0; l0 = fmaf(l0, al0, p0);
      a00 = a00 * al0 + p0 * vB0;
      a01 = a01 * al0 + p0 * vB1;
      const float nm1 = fmaxf(m1, d1);
      const float al1 = __expf(m1 - nm1);
      const float p1  = __expf(d1 - nm1);
      m1 = nm1; l1 = fmaf(l1, al1, p1);
      a10 = a10 * al1 + p1 * vB0;
      a11 = a11 * al1 + p1 * vB1;
      vB0 = ntl4(vrn + dbase);
      vB1 = ntl4(vrn + dbase + 4);
      mkB = mkn;
    }
  }

  if (sub == 0) {
    mred[stream][0] = m0; mred[stream][1] = l0;
    mred[stream][2] = m1; mred[stream][3] = l1;
  }
  __syncthreads();
  float M0 = -3.4e38f, M1 = -3.4e38f;
#pragma unroll
  for (int t = 0; t < 8; ++t) {
    M0 = fmaxf(M0, mred[t][0]);
    M1 = fmaxf(M1, mred[t][2]);
  }
  const float sc0 = __expf(m0 - M0);
  const float sc1 = __expf(m1 - M1);
  float* ab = &accbuf[stream][0];
  ab[dbase + 0] = a00.x * sc0; ab[dbase + 1] = a00.y * sc0;
  ab[dbase + 2] = a00.z * sc0; ab[dbase + 3] = a00.w * sc0;
  ab[dbase + 4] = a01.x * sc0; ab[dbase + 5] = a01.y * sc0;
  ab[dbase + 6] = a01.z * sc0; ab[dbase + 7] = a01.w * sc0;
  ab[256 + dbase + 0] = a10.x * sc1; ab[256 + dbase + 1] = a10.y * sc1;
  ab[256 + dbase + 2] = a10.z * sc1; ab[256 + dbase + 3] = a10.w * sc1;
  ab[256 + dbase + 4] = a11.x * sc1; ab[256 + dbase + 5] = a11.y * sc1;
  ab[256 + dbase + 6] = a11.z * sc1; ab[256 + dbase + 7] = a11.w * sc1;
  __syncthreads();

  if (tid == 0) {
    float L0 = 0.f, L1 = 0.f;
#pragma unroll
    for (int t = 0; t < 8; ++t) {
      L0 = fmaf(mred[t][1], __expf(mred[t][0] - M0), L0);
      L1 = fmaf(mred[t][3], __expf(mred[t][2] - M1), L1);
    }
    float2* mlp = (float2*)ml;
    const int mlbase = (((b * 8 + kv) * 8) + c) * 2;
    mlp[mlbase + 0] = make_float2(M0, L0);
    mlp[mlbase + 1] = make_float2(M1, L1);
  }

  const size_t obase = (size_t)((b * 8 + kv) * 8 + c) * 512;
  for (int t = tid; t < 512; t += 256) {
    float sum = 0.f;
#pragma unroll
    for (int st = 0; st < 8; ++st) sum += accbuf[st][t];
    opart[obase + t] = sum;     // cached: oproj re-reads heavily
  }
}

// ---------------------------------------------------------------------------
// Kernel D: fused combine + output projection partials. wo: NT loads.
__global__ __launch_bounds__(256) void oproj_fused_kernel(
    const float* __restrict__ opart, const float* __restrict__ ml,
    const float* __restrict__ wo, float* __restrict__ po) {
  __shared__ float xs[32][128];   // 16 KB

  const int t = threadIdx.x;
  const int ctile = blockIdx.x % 24;
  const int rem   = blockIdx.x / 24;
  const int kc    = rem >> 1;            // head 0..15
  const int kh    = rem & 1;             // K-half 0..1 (128 dims)
  const int kvh = kc >> 1, g = kc & 1;

  {
    const int b = t >> 3;
    const int dloc = (t & 7) * 16;
    const int kvb = b * 8 + kvh;
    const float2* mlp = (const float2*)ml;
    float2 mls[8];
    float M = -3.4e38f;
#pragma unroll
    for (int c = 0; c < 8; ++c) {
      mls[c] = mlp[(kvb * 8 + c) * 2 + g];
      M = fmaxf(M, mls[c].x);
    }
    float L = 0.f;
    f32x4 O[4];
#pragma unroll
    for (int q = 0; q < 4; ++q) O[q] = (f32x4){0.f, 0.f, 0.f, 0.f};
#pragma unroll
    for (int c = 0; c < 8; ++c) {
      const float wc = __expf(mls[c].x - M);
      L = fmaf(mls[c].y, wc, L);
      const float* src = opart +
          (size_t)(kvb * 8 + c) * 512 + g * 256 + kh * 128 + dloc;
#pragma unroll
      for (int q = 0; q < 4; ++q) O[q] += wc * ld4(src + q * 4);
    }
    const float invL = 1.f / L;
#pragma unroll
    for (int q = 0; q < 4; ++q) {
      *(f32x4*)(&xs[b][dloc + q * 4]) = O[q] * invL;
    }
  }
  __syncthreads();

  const int lane = t & 31;
  const int half = t >> 5;               // 0..7
  const int n = ctile * 128 + lane * 4;
  const float* wb = wo + (size_t)(kc * 256 + kh * 128) * 3072 + n;

  f32x4 acc[4];
#pragma unroll
  for (int j = 0; j < 4; ++j) acc[j] = (f32x4){0.f, 0.f, 0.f, 0.f};

  f32x4 wA[4], wB[4];
#define LDW(S, KK)                                                 \
  {                                                                \
    S[0] = ntl4(wb + (size_t)((KK) + 0) * 3072);                   \
    S[1] = ntl4(wb + (size_t)((KK) + 1) * 3072);                   \
    S[2] = ntl4(wb + (size_t)((KK) + 2) * 3072);                   \
    S[3] = ntl4(wb + (size_t)((KK) + 3) * 3072);                   \
  }
#define CMP(S, KK)                                                 \
  {                                                                \
    _Pragma("unroll")                                              \
    for (int j = 0; j < 4; ++j) {                                  \
      const f32x4 xv = *(const f32x4*)(&xs[half * 4 + j][(KK)]);   \
      acc[j] += xv.x * S[0];                                       \
      acc[j] += xv.y * S[1];                                       \
      acc[j] += xv.z * S[2];                                       \
      acc[j] += xv.w * S[3];                                       \
    }                                                              \
  }

  LDW(wA, 0);
  for (int k = 0; k < 128; k += 8) {
    LDW(wB, k + 4);
    CMP(wA, k);
    const int kn = (k + 8 < 128) ? (k + 8) : 0;
    LDW(wA, kn);
    CMP(wB, k + 4);
  }
#undef LDW
#undef CMP

#pragma unroll
  for (int j = 0; j < 4; ++j) {
    *(f32x4*)(po + ((size_t)(kc * 2 + kh) * 32 + half * 4 + j) * 3072 + n)
        = acc[j];
  }
}

// ---------------------------------------------------------------------------
// Kernel E: sum the 32 out-proj partials -> d_out. po: NT loads.
__global__ __launch_bounds__(256) void finalize_kernel(
    const float* __restrict__ po, float* __restrict__ out) {
  const int i = blockIdx.x * 256 + threadIdx.x;  // < 24576 float4s
  f32x4 acc = (f32x4){0.f, 0.f, 0.f, 0.f};
#pragma unroll
  for (int kc = 0; kc < 32; ++kc) {
    acc += ntl4(po + ((size_t)kc * 24576 + i) * 4);
  }
  *(f32x4*)((float*)out + (size_t)i * 4) = acc;
}

// ---------------------------------------------------------------------------
extern "C" void kernel_launch(void* const* d_in, const int* in_sizes, int n_in,
                              void* d_out, int out_size, void* d_ws, size_t ws_size,
                              hipStream_t stream) {
  (void)in_sizes; (void)n_in; (void)out_size; (void)ws_size;
  const float* x    = (const float*)d_in[0];
  const float* fcos = (const float*)d_in[1];
  const float* fsin = (const float*)d_in[2];
  const float* mask = (const float*)d_in[3];
  const float* ck   = (const float*)d_in[4];
  const float* cv   = (const float*)d_in[5];
  const float* wq   = (const float*)d_in[6];
  const float* wk   = (const float*)d_in[7];
  const float* wv   = (const float*)d_in[8];
  const float* wo   = (const float*)d_in[9];
  const int*   pos  = (const int*)d_in[10];

  float* ws    = (float*)d_ws;
  float* pqkv  = ws;                 // dead after reduce_rope
  float* opart = ws;                 // aliases pqkv (used after it's dead)
  float* ml    = ws + OFF_ML;
  float* xqkv  = ws + OFF_XQKV;
  float* po    = ws + OFF_PO;
  float* out   = (float*)d_out;

  qkv_partial_kernel<<<768, 256, 0, stream>>>(x, wq, wk, wv, pqkv);
  reduce_rope_kernel<<<160, 256, 0, stream>>>(pqkv, fcos, fsin, xqkv);
  attn_chunk_kernel<<<2048, 256, 0, stream>>>(xqkv, ck, cv, mask, pos, opart, ml);
  oproj_fused_kernel<<<768, 256, 0, stream>>>(opart, ml, wo, po);
  finalize_kernel<<<96, 256, 0, stream>>>(po, out);
}